// Round 5
// baseline (1099.786 us; speedup 1.0000x reference)
//
#include <hip/hip_runtime.h>

typedef __attribute__((ext_vector_type(8))) short bf16x8;
typedef __attribute__((ext_vector_type(16))) float f32x16;

#define B_ROWS 262144
#define K_CODES 1024
#define DIM 64
#define DELTA 0.015f

// output layout (floats)
#define OUT_ZQ 0
#define OUT_IDX 16777216
#define OUT_LOSS 17039360
#define OUT_NEWCS 17039361
#define OUT_NEWES 17040385
#define OUT_NEWW 17105921

// ws layout (float indices); ~10.9 MB total
#define WS_LOSS   0
#define WS_QCOUNT 1
#define WS_W2     16
#define WS_SMOOTH 1040
#define WS_WHI    2064      // ushort[65536], 16B aligned
#define WS_WLO    34832     // ushort[65536]
#define WS_CPART  67600     // 256 blocks * 128 codes
#define WS_EPART  100368    // 256 blocks * 128 codes * 64 dims
#define WS_MINI   2197520   // int[262144]; bit31 = ambiguous
#define WS_QUEUE  2459664   // int[262144]

static __device__ __forceinline__ unsigned short f2bf(float x) {
    unsigned u = __float_as_uint(x);
    return (unsigned short)((u + 0x7fffu + ((u >> 16) & 1u)) >> 16);  // RN-even
}
static __device__ __forceinline__ float bf2f(unsigned short u) {
    return __uint_as_float(((unsigned)u) << 16);
}

// Fused: bf16 hi/lo codebook split + w2 row norms.
__global__ __launch_bounds__(256) void vq_prep(const float* __restrict__ w,
                                               float* __restrict__ ws) {
    int i4 = blockIdx.x * 256 + threadIdx.x;  // 16384 float4s
    float4 v = ((const float4*)w)[i4];
    ushort4 h, l;
    h.x = f2bf(v.x); l.x = f2bf(v.x - bf2f(h.x));
    h.y = f2bf(v.y); l.y = f2bf(v.y - bf2f(h.y));
    h.z = f2bf(v.z); l.z = f2bf(v.z - bf2f(h.z));
    h.w = f2bf(v.w); l.w = f2bf(v.w - bf2f(h.w));
    ((ushort4*)(ws + WS_WHI))[i4] = h;
    ((ushort4*)(ws + WS_WLO))[i4] = l;
    float s = v.x * v.x + v.y * v.y + v.z * v.z + v.w * v.w;
    s += __shfl_xor(s, 1, 64);
    s += __shfl_xor(s, 2, 64);
    s += __shfl_xor(s, 4, 64);
    s += __shfl_xor(s, 8, 64);
    if ((threadIdx.x & 15) == 0) ws[WS_W2 + (i4 >> 4)] = s;
}

// MFMA 32x32x16 screening. Block = 4 waves x 32 rows = 128 rows, all 1024
// codes in 8 chunks of 128. LDS holds codebook fragments in MFMA-granule
// order: granule G at byte G*16, lane l reads base+l*16 -> sequential,
// conflict-free reads AND writes. Reg-prefetch double buffer for staging.
// dist = w2[k] - 2*dot (z2 constant per row, cancels in gaps).
__global__ __launch_bounds__(256, 3) void vq_screen_kernel(
    const float* __restrict__ z, float* __restrict__ ws) {
    __shared__ __align__(16) unsigned short lds_h[8192];  // 128 codes x 64 dims
    __shared__ __align__(16) unsigned short lds_l[8192];
    __shared__ float lds_w2[K_CODES];

    int tid = threadIdx.x;
    int l = tid & 63, wave = tid >> 6;
    int col = l & 31, hh = l >> 5;

    // w2 -> LDS once (full 1024)
    *(float4*)&lds_w2[tid * 4] = ((const float4*)(ws + WS_W2))[tid];

    // A fragments: wave covers 32 rows; lane row = col, k = s*16 + hh*8 + j
    int rowbase = blockIdx.x * 128 + wave * 32;
    const float* zr = z + (size_t)(rowbase + col) * DIM + hh * 8;
    bf16x8 ahi[4], alo[4];
#pragma unroll
    for (int s = 0; s < 4; ++s) {
        float4 f0 = *(const float4*)(zr + s * 16);
        float4 f1 = *(const float4*)(zr + s * 16 + 4);
        float tf[8] = {f0.x, f0.y, f0.z, f0.w, f1.x, f1.y, f1.z, f1.w};
#pragma unroll
        for (int j = 0; j < 8; ++j) {
            unsigned short hb = f2bf(tf[j]);
            ahi[s][j] = (short)hb;
            alo[s][j] = (short)f2bf(tf[j] - bf2f(hb));
        }
    }

    float mv[16], m2[16];
    int mi[16];
#pragma unroll
    for (int r = 0; r < 16; ++r) { mv[r] = 3.4e38f; m2[r] = 3.4e38f; mi[r] = 0; }

    const uint4* gh = (const uint4*)(ws + WS_WHI);
    const uint4* gl = (const uint4*)(ws + WS_WLO);

    // prefetch chunk 0: thread stages granules G = j*256+tid
    uint4 ph[4], pl[4];
#pragma unroll
    for (int j = 0; j < 4; ++j) {
        int G = j * 256 + tid;
        int gidx = ((G >> 8) * 32 + (G & 31)) * 8 + ((G >> 6) & 3) * 2 + ((G >> 5) & 1);
        ph[j] = gh[gidx];
        pl[j] = gl[gidx];
    }

    for (int cch = 0; cch < 8; ++cch) {
        __syncthreads();
#pragma unroll
        for (int j = 0; j < 4; ++j) {
            *(uint4*)&lds_h[(unsigned)(j * 256 + tid) * 8] = ph[j];
            *(uint4*)&lds_l[(unsigned)(j * 256 + tid) * 8] = pl[j];
        }
        __syncthreads();
        if (cch < 7) {
#pragma unroll
            for (int j = 0; j < 4; ++j) {
                int G = j * 256 + tid;
                int gidx = ((cch + 1) * 128 + (G >> 8) * 32 + (G & 31)) * 8 +
                           ((G >> 6) & 3) * 2 + ((G >> 5) & 1);
                ph[j] = gh[gidx];
                pl[j] = gl[gidx];
            }
        }

#pragma unroll
        for (int tl = 0; tl < 4; ++tl) {
            f32x16 acc = {0.f, 0.f, 0.f, 0.f, 0.f, 0.f, 0.f, 0.f,
                          0.f, 0.f, 0.f, 0.f, 0.f, 0.f, 0.f, 0.f};
#pragma unroll
            for (int s = 0; s < 4; ++s) {
                bf16x8 bh = *(const bf16x8*)&lds_h[(unsigned)(tl * 256 + s * 64 + l) * 8];
                bf16x8 bl = *(const bf16x8*)&lds_l[(unsigned)(tl * 256 + s * 64 + l) * 8];
                acc = __builtin_amdgcn_mfma_f32_32x32x16_bf16(alo[s], bh, acc, 0, 0, 0);
                acc = __builtin_amdgcn_mfma_f32_32x32x16_bf16(ahi[s], bl, acc, 0, 0, 0);
                acc = __builtin_amdgcn_mfma_f32_32x32x16_bf16(ahi[s], bh, acc, 0, 0, 0);
            }
            int cg = cch * 128 + tl * 32 + col;
            float w2v = lds_w2[cg];
#pragma unroll
            for (int r = 0; r < 16; ++r) {
                float d = fmaf(acc[r], -2.0f, w2v);
                bool lt = d < mv[r];
                m2[r] = lt ? mv[r] : fminf(m2[r], d);
                mv[r] = lt ? d : mv[r];
                mi[r] = lt ? cg : mi[r];
            }
        }
    }

    // reduce across 32 code-columns (lanes 0-31 / 32-63 hold disjoint rows)
#pragma unroll
    for (int o = 1; o < 32; o <<= 1) {
#pragma unroll
        for (int r = 0; r < 16; ++r) {
            float ov = __shfl_xor(mv[r], o, 64);
            float ov2 = __shfl_xor(m2[r], o, 64);
            int oi = __shfl_xor(mi[r], o, 64);
            float nm2 = fminf(fminf(m2[r], ov2), fmaxf(mv[r], ov));
            bool take = (ov < mv[r]) || (ov == mv[r] && oi < mi[r]);
            mv[r] = take ? ov : mv[r];
            mi[r] = take ? oi : mi[r];
            m2[r] = nm2;
        }
    }
    if (col == 0) {
#pragma unroll
        for (int r = 0; r < 16; ++r) {
            int row = rowbase + (r & 3) + 8 * (r >> 2) + 4 * hh;
            bool amb = (m2[r] - mv[r] <= DELTA);
            ((int*)ws)[WS_MINI + row] = mi[r] | (amb ? 0x80000000 : 0);
        }
    }
}

// Per-row: unambiguous -> write idx, z_q_st, loss; ambiguous -> enqueue.
__global__ __launch_bounds__(256) void vq_gather_kernel(
    const float* __restrict__ z, const float* __restrict__ w,
    float* __restrict__ ws, float* __restrict__ out) {
    __shared__ float lred[4];
    int tid = threadIdx.x;
    int row = blockIdx.x * 256 + tid;
    int enc = ((const int*)ws)[WS_MINI + row];
    float lsum = 0.f;
    if (enc >= 0) {
        int mi = enc;
        out[OUT_IDX + row] = (float)mi;
        const float4* zp = (const float4*)(z + (size_t)row * DIM);
        const float4* wq4 = (const float4*)(w + (size_t)mi * DIM);
        float4* outp = (float4*)(out + OUT_ZQ + (size_t)row * DIM);
#pragma unroll
        for (int j = 0; j < 16; ++j) {
            float4 x = zp[j];
            float4 qv = wq4[j];
            float4 st;
            st.x = x.x + (qv.x - x.x);
            st.y = x.y + (qv.y - x.y);
            st.z = x.z + (qv.z - x.z);
            st.w = x.w + (qv.w - x.w);
            outp[j] = st;
            float e0 = x.x - qv.x, e1 = x.y - qv.y, e2 = x.z - qv.z, e3 = x.w - qv.w;
            lsum += e0 * e0;
            lsum += e1 * e1;
            lsum += e2 * e2;
            lsum += e3 * e3;
        }
    } else {
        int pos = atomicAdd((int*)ws + WS_QCOUNT, 1);
        ((int*)ws)[WS_QUEUE + pos] = row;
    }
#pragma unroll
    for (int o = 32; o; o >>= 1) lsum += __shfl_down(lsum, o, 64);
    if ((tid & 63) == 0) lred[tid >> 6] = lsum;
    __syncthreads();
    if (tid == 0) atomicAdd(ws + WS_LOSS, lred[0] + lred[1] + lred[2] + lred[3]);
}

// One wave per ambiguous row: exact fp32 argmin (reference arithmetic).
__global__ __launch_bounds__(256) void vq_fixup_kernel(
    const float* __restrict__ z, const float* __restrict__ w,
    float* __restrict__ ws, float* __restrict__ out) {
    const float* __restrict__ w2 = ws + WS_W2;
    int count = ((const int*)ws)[WS_QCOUNT];
    int lane = threadIdx.x & 63;
    int wv = (blockIdx.x * 256 + threadIdx.x) >> 6;
    int nw = (gridDim.x * 256) >> 6;
    for (int qi = wv; qi < count; qi += nw) {
        int row = ((const int*)ws)[WS_QUEUE + qi];
        const float* zr = z + (size_t)row * DIM;
        float zloc[DIM];
#pragma unroll
        for (int d = 0; d < DIM; ++d) zloc[d] = zr[d];
        float z2 = 0.f;
#pragma unroll
        for (int d = 0; d < DIM; ++d) z2 = fmaf(zloc[d], zloc[d], z2);
        float best = 3.4e38f;
        int bi = 0;
        for (int i = 0; i < 16; ++i) {
            int c = i * 64 + lane;
            const float* wr = w + (size_t)c * DIM;
            float a = 0.f;
#pragma unroll
            for (int d = 0; d < DIM; ++d) a = fmaf(zloc[d], wr[d], a);
            float dd = (z2 - 2.f * a) + w2[c];
            if (dd < best) { best = dd; bi = c; }
        }
#pragma unroll
        for (int o = 1; o < 64; o <<= 1) {
            float ov = __shfl_xor(best, o, 64);
            int oi = __shfl_xor(bi, o, 64);
            if (ov < best || (ov == best && oi < bi)) { best = ov; bi = oi; }
        }
        float x = zr[lane];
        float qv = w[(size_t)bi * DIM + lane];
        out[OUT_ZQ + (size_t)row * DIM + lane] = x + (qv - x);
        float e = x - qv;
        float s = e * e;
#pragma unroll
        for (int o = 32; o; o >>= 1) s += __shfl_down(s, o, 64);
        if (lane == 0) {
            out[OUT_IDX + row] = (float)bi;
            atomicAdd(ws + WS_LOSS, s);
        }
    }
}

// Segment-sum via LDS accumulation: 8 code-splits x 32 row-slices.
// Each z row is gathered exactly once (by its code's split owner).
__global__ __launch_bounds__(256) void vq_embed_kernel(
    const float* __restrict__ z, const float* __restrict__ idx_f,
    float* __restrict__ ws) {
    __shared__ float eacc[128 * DIM];
    __shared__ float ecnt[128];
    int b = blockIdx.x;
    int cs = b & 7, rs = b >> 3;
    float lo = (float)(cs * 128), hi = (float)(cs * 128 + 128);
    int tid = threadIdx.x;
    int wave = tid >> 6, lane = tid & 63;

#pragma unroll
    for (int j = 0; j < 32; ++j) eacc[j * 256 + tid] = 0.f;
    if (tid < 128) ecnt[tid] = 0.f;
    __syncthreads();

    const float4* idx4 = (const float4*)idx_f;
    // wave scans 2048 rows in chunks of 256
    for (int it = 0; it < 8; ++it) {
        int base = rs * 8192 + wave * 2048 + it * 256;
        float4 f = idx4[(base >> 2) + lane];
#pragma unroll
        for (int c = 0; c < 4; ++c) {
            float fv = (c == 0) ? f.x : (c == 1) ? f.y : (c == 2) ? f.z : f.w;
            unsigned long long m = __ballot(fv >= lo && fv < hi);
            while (m) {
                int bb = __ffsll(m) - 1;
                m &= m - 1;
                int row = base + 4 * bb + c;
                float cf = __shfl(fv, bb, 64);
                int local = (int)cf - cs * 128;
                float val = z[(size_t)row * DIM + lane];
                atomicAdd(&eacc[local * DIM + lane], val);
                if (lane == 0) atomicAdd(&ecnt[local], 1.f);
            }
        }
    }
    __syncthreads();
#pragma unroll
    for (int j = 0; j < 32; ++j)
        ws[WS_EPART + (size_t)b * 8192 + j * 256 + tid] = eacc[j * 256 + tid];
    if (tid < 128) ws[WS_CPART + b * 128 + tid] = ecnt[tid];
}

__global__ __launch_bounds__(1024) void vq_finalize1_kernel(
    const float* __restrict__ ema_cs, float* __restrict__ ws,
    float* __restrict__ out) {
    int k = threadIdx.x;
    int cs = k >> 7, local = k & 127;
    float c = 0.f;
#pragma unroll
    for (int rs = 0; rs < 32; ++rs) c += ws[WS_CPART + (rs * 8 + cs) * 128 + local];
    float nc = 0.99f * ema_cs[k] + 0.01f * c;
    out[OUT_NEWCS + k] = nc;

    float s = nc;
#pragma unroll
    for (int o = 32; o; o >>= 1) s += __shfl_down(s, o, 64);
    __shared__ float red[16];
    __shared__ float n_sh;
    if ((k & 63) == 0) red[k >> 6] = s;
    __syncthreads();
    if (k == 0) {
        float n = 0.f;
#pragma unroll
        for (int i = 0; i < 16; ++i) n += red[i];
        n_sh = n;
        out[OUT_LOSS] = 0.25f * (ws[WS_LOSS] / 16777216.0f);
    }
    __syncthreads();
    float n = n_sh;
    ws[WS_SMOOTH + k] = (nc + 1e-5f) / (n + 0.01024f) * n;
}

__global__ __launch_bounds__(256) void vq_finalize2_kernel(
    const float* __restrict__ ema_es, const float* __restrict__ ws,
    float* __restrict__ out) {
    int i = blockIdx.x * 256 + threadIdx.x;  // 65536 elems = code*64+dim
    int code = i >> 6, dim = i & 63;
    int cs = code >> 7, local = code & 127;
    float e = 0.f;
#pragma unroll
    for (int rs = 0; rs < 32; ++rs)
        e += ws[WS_EPART + (size_t)(rs * 8 + cs) * 8192 + local * DIM + dim];
    float es = 0.99f * ema_es[i] + 0.01f * e;
    out[OUT_NEWES + i] = es;
    out[OUT_NEWW + i] = es / ws[WS_SMOOTH + code];
}

extern "C" void kernel_launch(void* const* d_in, const int* in_sizes, int n_in,
                              void* d_out, int out_size, void* d_ws, size_t ws_size,
                              hipStream_t stream) {
    const float* z = (const float*)d_in[0];
    const float* weight = (const float*)d_in[1];
    const float* ema_cs = (const float*)d_in[2];
    const float* ema_es = (const float*)d_in[3];
    float* out = (float*)d_out;
    float* ws = (float*)d_ws;

    hipMemsetAsync(ws, 0, 64, stream);  // loss + queue counter
    vq_prep<<<64, 256, 0, stream>>>(weight, ws);
    vq_screen_kernel<<<B_ROWS / 128, 256, 0, stream>>>(z, ws);
    vq_gather_kernel<<<B_ROWS / 256, 256, 0, stream>>>(z, weight, ws, out);
    vq_fixup_kernel<<<256, 256, 0, stream>>>(z, weight, ws, out);
    vq_embed_kernel<<<256, 256, 0, stream>>>(z, out + OUT_IDX, ws);
    vq_finalize1_kernel<<<1, 1024, 0, stream>>>(ema_cs, ws, out);
    vq_finalize2_kernel<<<256, 256, 0, stream>>>(ema_es, ws, out);
}

// Round 6
// 435.826 us; speedup vs baseline: 2.5235x; 2.5235x over previous
//
#include <hip/hip_runtime.h>

typedef __attribute__((ext_vector_type(8))) short bf16x8;
typedef __attribute__((ext_vector_type(4))) float f32x4;

#define B_ROWS 262144
#define K_CODES 1024
#define DIM 64
#define DELTA 0.015f

// output layout (floats)
#define OUT_ZQ 0
#define OUT_IDX 16777216
#define OUT_LOSS 17039360
#define OUT_NEWCS 17039361
#define OUT_NEWES 17040385
#define OUT_NEWW 17105921

// ws layout (float indices); ~10.9 MB total
#define WS_LOSS   0
#define WS_QCOUNT 1
#define WS_W2     16
#define WS_SMOOTH 1040
#define WS_WHIP   2064      // permuted hi codebook: 8192 granules x 16B
#define WS_WLOP   34832     // permuted lo codebook
#define WS_CPART  67600     // 256 blocks * 128 codes
#define WS_EPART  100368    // 256 blocks * 128 codes * 64 dims
#define WS_MINI   2197520   // int[262144]; bit31 = ambiguous
#define WS_QUEUE  2459664   // int[262144]

static __device__ __forceinline__ unsigned short f2bf(float x) {
    unsigned u = __float_as_uint(x);
    return (unsigned short)((u + 0x7fffu + ((u >> 16) & 1u)) >> 16);  // RN-even
}
static __device__ __forceinline__ float bf2f(unsigned short u) {
    return __uint_as_float(((unsigned)u) << 16);
}

static __device__ __forceinline__ void cvt_frag(const float* zrow, bf16x8& hi, bf16x8& lo) {
    float4 f0 = *(const float4*)zrow;
    float4 f1 = *(const float4*)(zrow + 4);
    float tf[8] = {f0.x, f0.y, f0.z, f0.w, f1.x, f1.y, f1.z, f1.w};
#pragma unroll
    for (int j = 0; j < 8; ++j) {
        unsigned short h = f2bf(tf[j]);
        hi[j] = (short)h;
        lo[j] = (short)f2bf(tf[j] - bf2f(h));
    }
}

// blocks 0..3: w2 row norms. blocks 4..35: permute codebook into MFMA-granule
// order: chunk c (128 codes), position p: granule = (code c*128+(p>>7)*16+(p&15),
// octet ((p>>6)&1)*4 + ((p>>4)&3)). Lane l of B-frag read maps to p = base + l.
__global__ __launch_bounds__(256) void vq_prep(const float* __restrict__ w,
                                               float* __restrict__ ws) {
    int b = blockIdx.x, tid = threadIdx.x;
    if (b < 4) {
        int k = b * 256 + tid;
        const float4* w4 = (const float4*)(w + (size_t)k * DIM);
        float s = 0.f;
#pragma unroll
        for (int j = 0; j < 16; ++j) {
            float4 v = w4[j];
            s += v.x * v.x + v.y * v.y + v.z * v.z + v.w * v.w;
        }
        ws[WS_W2 + k] = s;
    } else {
        int i = (b - 4) * 256 + tid;  // granule index 0..8191
        int p = i & 1023, c = i >> 10;
        int code = c * 128 + ((p >> 7) << 4) + (p & 15);
        int octet = ((p >> 6) & 1) * 4 + ((p >> 4) & 3);
        const float* src = w + (size_t)code * DIM + octet * 8;
        float4 f0 = *(const float4*)src;
        float4 f1 = *(const float4*)(src + 4);
        float tf[8] = {f0.x, f0.y, f0.z, f0.w, f1.x, f1.y, f1.z, f1.w};
        bf16x8 hv, lv;
#pragma unroll
        for (int j = 0; j < 8; ++j) {
            unsigned short hb = f2bf(tf[j]);
            hv[j] = (short)hb;
            lv[j] = (short)f2bf(tf[j] - bf2f(hb));
        }
        ((bf16x8*)(ws + WS_WHIP))[i] = hv;
        ((bf16x8*)(ws + WS_WLOP))[i] = lv;
    }
}

// MFMA 16x16x32 screening. Block = 4 waves x 64 rows = 256 rows, all 1024
// codes in 8 chunks of 128. Codebook staged from pre-permuted ws copy:
// granule G at LDS byte G*16; both staging writes and B-frag reads are
// lane-sequential 16B -> zero bank conflicts. 4 row-groups per wave:
// 24 MFMA per 4 ds_read_b128. dist = w2[k] - 2*dot (z2 cancels in gaps).
__global__ __launch_bounds__(256, 2) void vq_screen_kernel(
    const float* __restrict__ z, float* __restrict__ ws) {
    __shared__ __align__(16) unsigned short lds_h[1024 * 8];  // 16 KB
    __shared__ __align__(16) unsigned short lds_l[1024 * 8];  // 16 KB
    __shared__ float lds_w2[K_CODES];

    int tid = threadIdx.x;
    int l = tid & 63, wave = tid >> 6;
    int m = l & 15, q = l >> 4;

    *(float4*)&lds_w2[tid * 4] = ((const float4*)(ws + WS_W2))[tid];

    int rowbase = blockIdx.x * 256 + wave * 64;
    bf16x8 ahi[4][2], alo[4][2];
#pragma unroll
    for (int g = 0; g < 4; ++g) {
        const float* zr = z + (size_t)(rowbase + g * 16 + m) * DIM + q * 8;
        cvt_frag(zr, ahi[g][0], alo[g][0]);
        cvt_frag(zr + 32, ahi[g][1], alo[g][1]);
    }

    float mv[16], m2[16];
    int mi[16];
#pragma unroll
    for (int v = 0; v < 16; ++v) { mv[v] = 3.4e38f; m2[v] = 3.4e38f; mi[v] = 0; }

    const uint4* gh = (const uint4*)(ws + WS_WHIP);
    const uint4* gl = (const uint4*)(ws + WS_WLOP);

    for (int cch = 0; cch < 8; ++cch) {
        __syncthreads();
        {
            uint4 t0 = gh[cch * 1024 + 0 * 256 + tid];
            uint4 t1 = gh[cch * 1024 + 1 * 256 + tid];
            uint4 t2 = gh[cch * 1024 + 2 * 256 + tid];
            uint4 t3 = gh[cch * 1024 + 3 * 256 + tid];
            *(uint4*)&lds_h[(unsigned)(0 * 256 + tid) * 8] = t0;
            *(uint4*)&lds_h[(unsigned)(1 * 256 + tid) * 8] = t1;
            *(uint4*)&lds_h[(unsigned)(2 * 256 + tid) * 8] = t2;
            *(uint4*)&lds_h[(unsigned)(3 * 256 + tid) * 8] = t3;
        }
        {
            uint4 t0 = gl[cch * 1024 + 0 * 256 + tid];
            uint4 t1 = gl[cch * 1024 + 1 * 256 + tid];
            uint4 t2 = gl[cch * 1024 + 2 * 256 + tid];
            uint4 t3 = gl[cch * 1024 + 3 * 256 + tid];
            *(uint4*)&lds_l[(unsigned)(0 * 256 + tid) * 8] = t0;
            *(uint4*)&lds_l[(unsigned)(1 * 256 + tid) * 8] = t1;
            *(uint4*)&lds_l[(unsigned)(2 * 256 + tid) * 8] = t2;
            *(uint4*)&lds_l[(unsigned)(3 * 256 + tid) * 8] = t3;
        }
        __syncthreads();

#pragma unroll 2
        for (int tg = 0; tg < 8; ++tg) {
            bf16x8 bh0 = *(const bf16x8*)&lds_h[(unsigned)(tg * 128 + l) * 8];
            bf16x8 bh1 = *(const bf16x8*)&lds_h[(unsigned)(tg * 128 + 64 + l) * 8];
            bf16x8 bl0 = *(const bf16x8*)&lds_l[(unsigned)(tg * 128 + l) * 8];
            bf16x8 bl1 = *(const bf16x8*)&lds_l[(unsigned)(tg * 128 + 64 + l) * 8];
            int cg = cch * 128 + tg * 16 + m;
            float w2v = lds_w2[cg];
#pragma unroll
            for (int g = 0; g < 4; ++g) {
                f32x4 acc = {0.f, 0.f, 0.f, 0.f};
                acc = __builtin_amdgcn_mfma_f32_16x16x32_bf16(alo[g][0], bh0, acc, 0, 0, 0);
                acc = __builtin_amdgcn_mfma_f32_16x16x32_bf16(ahi[g][0], bl0, acc, 0, 0, 0);
                acc = __builtin_amdgcn_mfma_f32_16x16x32_bf16(alo[g][1], bh1, acc, 0, 0, 0);
                acc = __builtin_amdgcn_mfma_f32_16x16x32_bf16(ahi[g][1], bl1, acc, 0, 0, 0);
                acc = __builtin_amdgcn_mfma_f32_16x16x32_bf16(ahi[g][0], bh0, acc, 0, 0, 0);
                acc = __builtin_amdgcn_mfma_f32_16x16x32_bf16(ahi[g][1], bh1, acc, 0, 0, 0);
#pragma unroll
                for (int r = 0; r < 4; ++r) {
                    int v = g * 4 + r;
                    float d = fmaf(acc[r], -2.0f, w2v);
                    bool lt = d < mv[v];
                    m2[v] = lt ? mv[v] : fminf(m2[v], d);
                    mv[v] = lt ? d : mv[v];
                    mi[v] = lt ? cg : mi[v];
                }
            }
        }
    }

    // reduce across 16 code-lanes sharing q (same rows, different codes)
#pragma unroll
    for (int o = 1; o < 16; o <<= 1) {
#pragma unroll
        for (int v = 0; v < 16; ++v) {
            float ov = __shfl_xor(mv[v], o, 64);
            float ov2 = __shfl_xor(m2[v], o, 64);
            int oi = __shfl_xor(mi[v], o, 64);
            float nm2 = fminf(fminf(m2[v], ov2), fmaxf(mv[v], ov));
            bool take = (ov < mv[v]) || (ov == mv[v] && oi < mi[v]);
            mv[v] = take ? ov : mv[v];
            mi[v] = take ? oi : mi[v];
            m2[v] = nm2;
        }
    }
    if (m == 0) {
#pragma unroll
        for (int v = 0; v < 16; ++v) {
            int g = v >> 2, r = v & 3;
            int row = rowbase + g * 16 + q * 4 + r;  // C/D: row=(lane>>4)*4+reg
            bool amb = (m2[v] - mv[v] <= DELTA);
            ((int*)ws)[WS_MINI + row] = mi[v] | (amb ? 0x80000000 : 0);
        }
    }
}

// Per-row: unambiguous -> write idx, z_q_st, loss; ambiguous -> enqueue.
__global__ __launch_bounds__(256) void vq_gather_kernel(
    const float* __restrict__ z, const float* __restrict__ w,
    float* __restrict__ ws, float* __restrict__ out) {
    __shared__ float lred[4];
    int tid = threadIdx.x;
    int row = blockIdx.x * 256 + tid;
    int enc = ((const int*)ws)[WS_MINI + row];
    float lsum = 0.f;
    if (enc >= 0) {
        int mi = enc;
        out[OUT_IDX + row] = (float)mi;
        const float4* zp = (const float4*)(z + (size_t)row * DIM);
        const float4* wq4 = (const float4*)(w + (size_t)mi * DIM);
        float4* outp = (float4*)(out + OUT_ZQ + (size_t)row * DIM);
#pragma unroll
        for (int j = 0; j < 16; ++j) {
            float4 x = zp[j];
            float4 qv = wq4[j];
            float4 st;
            st.x = x.x + (qv.x - x.x);
            st.y = x.y + (qv.y - x.y);
            st.z = x.z + (qv.z - x.z);
            st.w = x.w + (qv.w - x.w);
            outp[j] = st;
            float e0 = x.x - qv.x, e1 = x.y - qv.y, e2 = x.z - qv.z, e3 = x.w - qv.w;
            lsum += e0 * e0;
            lsum += e1 * e1;
            lsum += e2 * e2;
            lsum += e3 * e3;
        }
    } else {
        int pos = atomicAdd((int*)ws + WS_QCOUNT, 1);
        ((int*)ws)[WS_QUEUE + pos] = row;
    }
#pragma unroll
    for (int o = 32; o; o >>= 1) lsum += __shfl_down(lsum, o, 64);
    if ((tid & 63) == 0) lred[tid >> 6] = lsum;
    __syncthreads();
    if (tid == 0) atomicAdd(ws + WS_LOSS, lred[0] + lred[1] + lred[2] + lred[3]);
}

// One wave per ambiguous row: exact fp32 argmin (reference arithmetic).
__global__ __launch_bounds__(256) void vq_fixup_kernel(
    const float* __restrict__ z, const float* __restrict__ w,
    float* __restrict__ ws, float* __restrict__ out) {
    const float* __restrict__ w2 = ws + WS_W2;
    int count = ((const int*)ws)[WS_QCOUNT];
    int lane = threadIdx.x & 63;
    int wv = (blockIdx.x * 256 + threadIdx.x) >> 6;
    int nw = (gridDim.x * 256) >> 6;
    for (int qi = wv; qi < count; qi += nw) {
        int row = ((const int*)ws)[WS_QUEUE + qi];
        const float* zr = z + (size_t)row * DIM;
        float zloc[DIM];
#pragma unroll
        for (int d = 0; d < DIM; ++d) zloc[d] = zr[d];
        float z2 = 0.f;
#pragma unroll
        for (int d = 0; d < DIM; ++d) z2 = fmaf(zloc[d], zloc[d], z2);
        float best = 3.4e38f;
        int bi = 0;
        for (int i = 0; i < 16; ++i) {
            int c = i * 64 + lane;
            const float* wr = w + (size_t)c * DIM;
            float a = 0.f;
#pragma unroll
            for (int d = 0; d < DIM; ++d) a = fmaf(zloc[d], wr[d], a);
            float dd = (z2 - 2.f * a) + w2[c];
            if (dd < best) { best = dd; bi = c; }
        }
#pragma unroll
        for (int o = 1; o < 64; o <<= 1) {
            float ov = __shfl_xor(best, o, 64);
            int oi = __shfl_xor(bi, o, 64);
            if (ov < best || (ov == best && oi < bi)) { best = ov; bi = oi; }
        }
        float x = zr[lane];
        float qv = w[(size_t)bi * DIM + lane];
        out[OUT_ZQ + (size_t)row * DIM + lane] = x + (qv - x);
        float e = x - qv;
        float s = e * e;
#pragma unroll
        for (int o = 32; o; o >>= 1) s += __shfl_down(s, o, 64);
        if (lane == 0) {
            out[OUT_IDX + row] = (float)bi;
            atomicAdd(ws + WS_LOSS, s);
        }
    }
}

// Segment-sum: 8 code-splits x 32 row-slices. Two-phase per batch: ballot-
// compact matched rows into an LDS list, then gather 4 rows per step
// (independent loads -> 4x memory-level parallelism). LDS accumulate.
__global__ __launch_bounds__(256) void vq_embed_kernel(
    const float* __restrict__ z, const float* __restrict__ idx_f,
    float* __restrict__ ws) {
    __shared__ float eacc[128 * DIM];  // 32 KB
    __shared__ float ecnt[128];
    __shared__ int lists[4][256];
    int b = blockIdx.x;
    int cs = b & 7, rs = b >> 3;
    float lo = (float)(cs * 128), hi = lo + 128.f;
    int tid = threadIdx.x;
    int wave = tid >> 6, lane = tid & 63;

#pragma unroll
    for (int j = 0; j < 32; ++j) eacc[j * 256 + tid] = 0.f;
    if (tid < 128) ecnt[tid] = 0.f;
    __syncthreads();

    const float4* idx4 = (const float4*)idx_f;
    unsigned long long lanebits = (1ull << lane) - 1ull;
    for (int it = 0; it < 8; ++it) {
        int base = rs * 8192 + wave * 2048 + it * 256;
        float4 f = idx4[(base >> 2) + lane];
        int cnt = 0;
#pragma unroll
        for (int c = 0; c < 4; ++c) {
            float fv = (c == 0) ? f.x : (c == 1) ? f.y : (c == 2) ? f.z : f.w;
            bool match = (fv >= lo && fv < hi);
            unsigned long long mmask = __ballot(match);
            if (match) {
                int pos = cnt + __popcll(mmask & lanebits);
                int row = base + 4 * lane + c;
                int local = (int)fv - cs * 128;
                lists[wave][pos] = (row << 7) | local;
                atomicAdd(&ecnt[local], 1.f);
            }
            cnt += __popcll(mmask);
        }
        int j = 0;
        for (; j + 4 <= cnt; j += 4) {
            int e0 = lists[wave][j], e1 = lists[wave][j + 1];
            int e2 = lists[wave][j + 2], e3 = lists[wave][j + 3];
            float v0 = z[(size_t)(e0 >> 7) * DIM + lane];
            float v1 = z[(size_t)(e1 >> 7) * DIM + lane];
            float v2 = z[(size_t)(e2 >> 7) * DIM + lane];
            float v3 = z[(size_t)(e3 >> 7) * DIM + lane];
            atomicAdd(&eacc[(e0 & 127) * DIM + lane], v0);
            atomicAdd(&eacc[(e1 & 127) * DIM + lane], v1);
            atomicAdd(&eacc[(e2 & 127) * DIM + lane], v2);
            atomicAdd(&eacc[(e3 & 127) * DIM + lane], v3);
        }
        for (; j < cnt; ++j) {
            int e = lists[wave][j];
            float v = z[(size_t)(e >> 7) * DIM + lane];
            atomicAdd(&eacc[(e & 127) * DIM + lane], v);
        }
    }
    __syncthreads();
#pragma unroll
    for (int j = 0; j < 32; ++j)
        ws[WS_EPART + (size_t)b * 8192 + j * 256 + tid] = eacc[j * 256 + tid];
    if (tid < 128) ws[WS_CPART + b * 128 + tid] = ecnt[tid];
}

__global__ __launch_bounds__(1024) void vq_finalize1_kernel(
    const float* __restrict__ ema_cs, float* __restrict__ ws,
    float* __restrict__ out) {
    int k = threadIdx.x;
    int cs = k >> 7, local = k & 127;
    float c = 0.f;
#pragma unroll
    for (int rs = 0; rs < 32; ++rs) c += ws[WS_CPART + (rs * 8 + cs) * 128 + local];
    float nc = 0.99f * ema_cs[k] + 0.01f * c;
    out[OUT_NEWCS + k] = nc;

    float s = nc;
#pragma unroll
    for (int o = 32; o; o >>= 1) s += __shfl_down(s, o, 64);
    __shared__ float red[16];
    __shared__ float n_sh;
    if ((k & 63) == 0) red[k >> 6] = s;
    __syncthreads();
    if (k == 0) {
        float n = 0.f;
#pragma unroll
        for (int i = 0; i < 16; ++i) n += red[i];
        n_sh = n;
        out[OUT_LOSS] = 0.25f * (ws[WS_LOSS] / 16777216.0f);
    }
    __syncthreads();
    float n = n_sh;
    ws[WS_SMOOTH + k] = (nc + 1e-5f) / (n + 0.01024f) * n;
}

__global__ __launch_bounds__(256) void vq_finalize2_kernel(
    const float* __restrict__ ema_es, const float* __restrict__ ws,
    float* __restrict__ out) {
    int i = blockIdx.x * 256 + threadIdx.x;  // 65536 elems = code*64+dim
    int code = i >> 6, dim = i & 63;
    int cs = code >> 7, local = code & 127;
    float e = 0.f;
#pragma unroll
    for (int rs = 0; rs < 32; ++rs)
        e += ws[WS_EPART + (size_t)(rs * 8 + cs) * 8192 + local * DIM + dim];
    float es = 0.99f * ema_es[i] + 0.01f * e;
    out[OUT_NEWES + i] = es;
    out[OUT_NEWW + i] = es / ws[WS_SMOOTH + code];
}

extern "C" void kernel_launch(void* const* d_in, const int* in_sizes, int n_in,
                              void* d_out, int out_size, void* d_ws, size_t ws_size,
                              hipStream_t stream) {
    const float* z = (const float*)d_in[0];
    const float* weight = (const float*)d_in[1];
    const float* ema_cs = (const float*)d_in[2];
    const float* ema_es = (const float*)d_in[3];
    float* out = (float*)d_out;
    float* ws = (float*)d_ws;

    hipMemsetAsync(ws, 0, 64, stream);  // loss + queue counter
    vq_prep<<<36, 256, 0, stream>>>(weight, ws);
    vq_screen_kernel<<<B_ROWS / 256, 256, 0, stream>>>(z, ws);
    vq_gather_kernel<<<B_ROWS / 256, 256, 0, stream>>>(z, weight, ws, out);
    vq_fixup_kernel<<<256, 256, 0, stream>>>(z, weight, ws, out);
    vq_embed_kernel<<<256, 256, 0, stream>>>(z, out + OUT_IDX, ws);
    vq_finalize1_kernel<<<1, 1024, 0, stream>>>(ema_cs, ws, out);
    vq_finalize2_kernel<<<256, 256, 0, stream>>>(ema_es, ws, out);
}